// Round 5
// baseline (1833.655 us; speedup 1.0000x reference)
//
#include <hip/hip_runtime.h>
#include <hip/hip_fp16.h>

#define NSLICE 8     // dst slices, mapped to XCDs via blockIdx & 7
#define EPB 2048     // edges scanned per block (256 threads x 8)

// ---------- preprocessing: padded-CSR build (exact degrees, no cap) ----------
// v5: ELL (25.6MB sparse, 64-slot rows) -> padded CSR (~8MB dense).
// Rationale (R4 counters): ell_fill burned 74us with FETCH=50MB / WRITE=65-73MB
// (write-allocate RMW thrash: 16 scattered-in-time writes per 128B line spread
// over 25.6MB), and each conv re-read the ~96B prefix of each 256B row (~2x
// line-granule waste). CSR rows are 8-aligned, exact-length, allocated via
// per-slice atomic bump (no prefix scan; row order is irrelevant, only
// disjointness). Per-slice col regions keep fill writes XCD-local and avoid
// cross-XCD false sharing. NT hints reverted everywhere (R4: +67us).

// pass 1: exact degree count. Block b: dst slice (b&7) -> XCD-local atomics.
__global__ __launch_bounds__(256) void count_kernel(
    const int* __restrict__ edges, int* __restrict__ deg,
    int e, int n, int slice_sz) {
    int slice = blockIdx.x & (NSLICE - 1);
    int chunk = blockIdx.x >> 3;
    int lo = slice * slice_sz;
    int hi = min(n, lo + slice_sz);
    int base = chunk * EPB + threadIdx.x;
    int d[EPB / 256];
#pragma unroll
    for (int k = 0; k < EPB / 256; ++k) {
        int i = base + k * 256;
        int valid = i < e;
        int ii = valid ? i : 0;       // safe address; result discarded if !valid
        int dv = edges[e + ii];       // independent batched dst loads
        d[k] = valid ? dv : -1;       // -1 fails every slice filter
    }
#pragma unroll
    for (int k = 0; k < EPB / 256; ++k) {
        int dv = d[k];
        if (dv < lo || dv >= hi) continue;
        atomicAdd(&deg[dv], 1);
    }
}

// pass 2: per-node constants + CSR row allocation (per-slice bump) + padding.
// Row length padded to x8 with phantom node n (its g-row is zero -> adds 0).
__global__ void nodeconst_kernel(const int* __restrict__ deg, int* __restrict__ alloc8,
                                 float* __restrict__ rs, float* __restrict__ sq,
                                 float* __restrict__ wdeg, int* __restrict__ rowp,
                                 int* __restrict__ cur, int* __restrict__ col,
                                 int n, int slice_sz, int rcap) {
    int i = blockIdx.x * blockDim.x + threadIdx.x;
    if (i > n) return;  // includes phantom node n (deg 0)
    int v = (i < n) ? deg[i] : 0;
    float d = (float)max(v, 1);
    float r = rsqrtf(d);
    rs[i] = r;
    sq[i] = sqrtf(d);
    wdeg[i] = 0.9f * r * r;
    int p = (v + 7) & ~7;                       // padded row length
    int slice = (i < n) ? (i / slice_sz) : 0;   // phantom: p=0, slice moot
    int base = slice * rcap + atomicAdd(&alloc8[slice], p);  // wave-aggregated
    rowp[i] = base;
    cur[i] = base;   // fill cursor starts at row base
    for (int k = v; k < p; ++k) col[base + k] = n;  // phantom padding
}

// pass 3: CSR fill. Same slice/chunk decomposition as count; writes land in
// this slice's ~1MB col region -> L2-resident, no write-allocate thrash.
__global__ __launch_bounds__(256) void csr_fill(
    const int* __restrict__ edges, int* __restrict__ cur,
    int* __restrict__ col, int e, int n, int slice_sz, int rcap) {
    int slice = blockIdx.x & (NSLICE - 1);
    int chunk = blockIdx.x >> 3;
    int lo = slice * slice_sz;
    int hi = min(n, lo + slice_sz);
    int lim = (slice + 1) * rcap;   // region bound (OOB guard; never hit)
    int base = chunk * EPB + threadIdx.x;
    int d[EPB / 256], s[EPB / 256];
#pragma unroll
    for (int k = 0; k < EPB / 256; ++k) {
        int i = base + k * 256;
        int valid = i < e;
        int ii = valid ? i : 0;
        int dv = edges[e + ii];
        int sv = edges[ii];
        d[k] = valid ? dv : -1;
        s[k] = sv;
    }
#pragma unroll
    for (int k = 0; k < EPB / 256; ++k) {
        int dv = d[k];
        if (dv < lo || dv >= hi) continue;
        int slot = atomicAdd(&cur[dv], 1);
        if (slot < lim) col[slot] = s[k];
    }
}

// g = rs (.) x, fp32 -> fp16. One thread per feature pair. Covers phantom
// node n (writes zeros; never reads x out of bounds).
__global__ void prescale_kernel(const float2* __restrict__ x2, const float* __restrict__ rs,
                                __half2* __restrict__ g, int n) {
    int i = blockIdx.x * blockDim.x + threadIdx.x;
    int node = i >> 4;
    if (node > n) return;
    if (node == n) { g[i] = __floats2half2_rn(0.f, 0.f); return; }
    float2 v = x2[i];
    float r = rs[node];
    g[i] = __floats2half2_rn(v.x * r, v.y * r);
}

// ---------- g-space conv (fp16 rows, packed-fp16 partial accum, padded CSR) ---
// g_out[d] = wdeg[d] * sum_{s in N(d)} g[s] + 0.1 * g0[d]
// 8 lanes per node, lane owns 4 halfs (8B; 8 lanes = one 64B row = 1 line).
// 8-edge rounds; entries coop-loaded + __shfl(width=8) broadcast; 8 indep
// gathers/round. Accumulation: v_pk_add_f16 into 4 half2-pair chains,
// flushed to fp32 every 2 rounds (wave-uniform) + once after the loop.
// v5: index stream is dense CSR (j0 = rowp[node]); plain (cached) loads.

union H4 {
    uint2 u;
    __half2 h[2];
};

__global__ __launch_bounds__(256) void conv_kernel(
    const uint2* __restrict__ gin, const uint2* __restrict__ g0,
    uint2* __restrict__ gout, const int* __restrict__ deg,
    const int* __restrict__ rowp, const int* __restrict__ col,
    const float* __restrict__ wdeg, int n) {
    int gid = blockIdx.x * blockDim.x + threadIdx.x;
    int node = gid >> 3;
    int q = gid & 7;
    if (node > n) return;  // phantom node n: deg 0 -> writes 0.1*g0 = 0
    int dg = deg[node];    // exact (deg[n]==0 from memset)
    int trips = (dg + 7) >> 3;  // rounds of 8 edges (CSR padded to x8)
    int j0 = rowp[node];
    float w = wdeg[node];
    H4 g0v;
    g0v.u = g0[gid];  // issued early; latency overlaps the loop
    // fp32 master accumulators
    float ax = 0.f, ay = 0.f, az = 0.f, aw = 0.f;
    // fp16 packed partial accumulators: 4 chains x 2 half2 (lo=feats01, hi=feats23)
    __half2 b0l = __floats2half2_rn(0.f, 0.f), b0h = b0l;
    __half2 b1l = b0l, b1h = b0l;
    __half2 b2l = b0l, b2h = b0l;
    __half2 b3l = b0l, b3h = b0l;
    int scur = col[j0 + q];  // unused if trips==0; region slack covers it
    for (int r = 0; r < trips; ++r) {
        int snext = col[j0 + (r + 1) * 8 + q];  // prefetch (dense; slack-padded)
        int s0 = __shfl(scur, 0, 8), s1 = __shfl(scur, 1, 8);
        int s2 = __shfl(scur, 2, 8), s3 = __shfl(scur, 3, 8);
        int s4 = __shfl(scur, 4, 8), s5 = __shfl(scur, 5, 8);
        int s6 = __shfl(scur, 6, 8), s7 = __shfl(scur, 7, 8);
        H4 v0, v1, v2, v3, v4, v5, v6, v7;
        v0.u = gin[(size_t)s0 * 8 + q];
        v1.u = gin[(size_t)s1 * 8 + q];
        v2.u = gin[(size_t)s2 * 8 + q];
        v3.u = gin[(size_t)s3 * 8 + q];
        v4.u = gin[(size_t)s4 * 8 + q];
        v5.u = gin[(size_t)s5 * 8 + q];
        v6.u = gin[(size_t)s6 * 8 + q];
        v7.u = gin[(size_t)s7 * 8 + q];
        b0l = __hadd2(b0l, v0.h[0]); b0h = __hadd2(b0h, v0.h[1]);
        b1l = __hadd2(b1l, v1.h[0]); b1h = __hadd2(b1h, v1.h[1]);
        b2l = __hadd2(b2l, v2.h[0]); b2h = __hadd2(b2h, v2.h[1]);
        b3l = __hadd2(b3l, v3.h[0]); b3h = __hadd2(b3h, v3.h[1]);
        b0l = __hadd2(b0l, v4.h[0]); b0h = __hadd2(b0h, v4.h[1]);
        b1l = __hadd2(b1l, v5.h[0]); b1h = __hadd2(b1h, v5.h[1]);
        b2l = __hadd2(b2l, v6.h[0]); b2h = __hadd2(b2h, v6.h[1]);
        b3l = __hadd2(b3l, v7.h[0]); b3h = __hadd2(b3h, v7.h[1]);
        if (r & 1) {  // wave-uniform flush every 2 rounds (max 16 fp16 adds)
            float2 t;
            t = __half22float2(b0l); ax += t.x; ay += t.y;
            t = __half22float2(b0h); az += t.x; aw += t.y;
            t = __half22float2(b1l); ax += t.x; ay += t.y;
            t = __half22float2(b1h); az += t.x; aw += t.y;
            t = __half22float2(b2l); ax += t.x; ay += t.y;
            t = __half22float2(b2h); az += t.x; aw += t.y;
            t = __half22float2(b3l); ax += t.x; ay += t.y;
            t = __half22float2(b3h); az += t.x; aw += t.y;
            b0l = __floats2half2_rn(0.f, 0.f); b0h = b0l;
            b1l = b0l; b1h = b0l;
            b2l = b0l; b2h = b0l;
            b3l = b0l; b3h = b0l;
        }
        scur = snext;
    }
    {   // final flush (covers trailing odd round; zeros if already flushed)
        float2 t;
        t = __half22float2(b0l); ax += t.x; ay += t.y;
        t = __half22float2(b0h); az += t.x; aw += t.y;
        t = __half22float2(b1l); ax += t.x; ay += t.y;
        t = __half22float2(b1h); az += t.x; aw += t.y;
        t = __half22float2(b2l); ax += t.x; ay += t.y;
        t = __half22float2(b2h); az += t.x; aw += t.y;
        t = __half22float2(b3l); ax += t.x; ay += t.y;
        t = __half22float2(b3h); az += t.x; aw += t.y;
    }
    float2 g0lo = __half22float2(g0v.h[0]);
    float2 g0hi = __half22float2(g0v.h[1]);
    float rx = w * ax + 0.1f * g0lo.x;
    float ry = w * ay + 0.1f * g0lo.y;
    float rz = w * az + 0.1f * g0hi.x;
    float rw = w * aw + 0.1f * g0hi.y;
    H4 o;
    o.h[0] = __floats2half2_rn(rx, ry);
    o.h[1] = __floats2half2_rn(rz, rw);
    gout[gid] = o.u;
}

// ---------- per-(node,feature) MLP, fused with g->h and h->g conversions ----------
// Covers phantom node n: writes zero (mlp(0) != 0, so explicit).

__global__ __launch_bounds__(256) void mlp_kernel(
    const __half* __restrict__ gin, __half* __restrict__ gout,
    const float* __restrict__ rs, const float* __restrict__ sq,
    const float* __restrict__ emb,   // [32][6]
    const float* __restrict__ W1,    // [7][9] row-major
    const float* __restrict__ b1,    // [9]
    const float* __restrict__ W2,    // [9]
    const float* __restrict__ b2,    // [1]
    int n) {
    __shared__ float c[32][9];
    __shared__ float w0[9], w2[9];
    __shared__ float b2s;
    int tid = threadIdx.x;
    for (int i = tid; i < 288; i += blockDim.x) {
        int f = i / 9, jj = i % 9;
        float acc = b1[jj];
#pragma unroll
        for (int k = 0; k < 6; ++k) acc += emb[f * 6 + k] * W1[(1 + k) * 9 + jj];
        c[f][jj] = acc;
    }
    if (tid < 9) { w0[tid] = W1[tid]; w2[tid] = W2[tid]; }
    if (tid == 0) b2s = b2[0];
    __syncthreads();
    int gid = blockIdx.x * blockDim.x + tid;
    int node = gid >> 5;
    if (node > n) return;
    if (node == n) { gout[gid] = __float2half_rn(0.f); return; }
    int f = gid & 31;
    float xv = __half2float(gin[gid]) * sq[node];
    float acc = b2s;
#pragma unroll
    for (int jj = 0; jj < 9; ++jj)
        acc += fmaxf(xv * w0[jj] + c[f][jj], 0.0f) * w2[jj];
    gout[gid] = __float2half_rn(acc * rs[node]);
}

// ---------- output projection (fused g->h): out = (sq .* g) @ Wout + bout ----------

__global__ __launch_bounds__(256) void out_kernel(
    const __half* __restrict__ g, const float* __restrict__ sq,
    const float* __restrict__ Wout, const float* __restrict__ bout,
    float* __restrict__ out, int n) {
    __shared__ float w[32 * 16];
    __shared__ float bo[16];
    int tid = threadIdx.x;
    for (int i = tid; i < 512; i += blockDim.x) w[i] = Wout[i];
    if (tid < 16) bo[tid] = bout[tid];
    __syncthreads();
    int gid = blockIdx.x * blockDim.x + tid;
    int node = gid >> 4;
    int cls = gid & 15;
    if (node >= n) return;
    const __half* gr = g + (size_t)node * 32;
    float acc = 0.0f;
#pragma unroll
    for (int f = 0; f < 32; ++f) acc += __half2float(gr[f]) * w[f * 16 + cls];
    out[gid] = acc * sq[node] + bo[cls];
}

extern "C" void kernel_launch(void* const* d_in, const int* in_sizes, int n_in,
                              void* d_out, int out_size, void* d_ws, size_t ws_size,
                              hipStream_t stream) {
    const float* x    = (const float*)d_in[0];
    const int* edges  = (const int*)d_in[1];
    const float* emb  = (const float*)d_in[2];
    const float* W1   = (const float*)d_in[3];
    const float* b1   = (const float*)d_in[4];
    const float* W2   = (const float*)d_in[5];
    const float* b2   = (const float*)d_in[6];
    const float* Wout = (const float*)d_in[7];
    const float* bout = (const float*)d_in[8];
    float* out        = (float*)d_out;

    const int N = in_sizes[0] / 32;
    const int E = in_sizes[1] / 2;

    const int slice_sz = (N + NSLICE - 1) / NSLICE;
    // per-slice col region capacity (ints): expected edges/slice (E/8) +
    // padding bound (<8*slice_sz) + skew/prefetch slack. Never overflows for
    // uniform-random dst (sigma ~ 420 edges); guarded in csr_fill anyway.
    const int RCAP = E / NSLICE + 8 * slice_sz + 4096;

    size_t off = 0;
    auto walloc = [&](size_t bytes) {
        void* p = (char*)d_ws + off;
        off += (bytes + 255) & ~(size_t)255;
        return p;
    };
    // all per-node arrays sized N+1 for the phantom (dummy) node N
    int*     deg   = (int*)    walloc((size_t)(N + 1 + 8) * 4);  // +8: alloc8
    int*     alloc8= deg + (N + 1);
    float*   rs    = (float*)  walloc((size_t)(N + 1) * 4);
    float*   sq    = (float*)  walloc((size_t)(N + 1) * 4);
    float*   wdeg  = (float*)  walloc((size_t)(N + 1) * 4);
    int*     rowp  = (int*)    walloc((size_t)(N + 1) * 4);
    int*     cur   = (int*)    walloc((size_t)(N + 1) * 4);
    int*     col   = (int*)    walloc((size_t)NSLICE * RCAP * 4 + 256);
    __half*  g0buf = (__half*) walloc((size_t)(N + 1) * 32 * 2);
    __half*  bufA  = (__half*) walloc((size_t)(N + 1) * 32 * 2);
    __half*  bufB  = (__half*) walloc((size_t)(N + 1) * 32 * 2);

    hipMemsetAsync(deg, 0, (size_t)(N + 1 + 8) * 4, stream);  // deg + alloc8

    const int chunks = (E + EPB - 1) / EPB;
    count_kernel<<<chunks * NSLICE, 256, 0, stream>>>(edges, deg, E, N, slice_sz);
    nodeconst_kernel<<<(N + 1 + 255) / 256, 256, 0, stream>>>(
        deg, alloc8, rs, sq, wdeg, rowp, cur, col, N, slice_sz, RCAP);
    csr_fill<<<chunks * NSLICE, 256, 0, stream>>>(edges, cur, col, E, N, slice_sz, RCAP);

    const int conv_blocks = ((N + 1) * 8 + 255) / 256;
    const int elem_blocks = ((N + 1) * 32 + 255) / 256;
    const int pair_blocks = ((N + 1) * 16 + 255) / 256;

    prescale_kernel<<<pair_blocks, 256, 0, stream>>>((const float2*)x, rs,
                                                     (__half2*)g0buf, N);

    // diffuse #1 in g-space (g0 = g0buf); 10 iters ends in bufB
    {
        const uint2* gin = (const uint2*)g0buf;
        for (int it = 0; it < 10; ++it) {
            uint2* go = (uint2*)((it & 1) ? bufB : bufA);
            conv_kernel<<<conv_blocks, 256, 0, stream>>>(gin, (const uint2*)g0buf, go,
                                                         deg, rowp, col, wdeg, N);
            gin = go;
        }
    }
    // MLP (g->h, mlp, h->g): bufB -> g0buf (becomes g0 of diffuse #2)
    mlp_kernel<<<elem_blocks, 256, 0, stream>>>(bufB, g0buf, rs, sq, emb, W1, b1, W2, b2, N);

    // diffuse #2 in g-space (g0 = g0buf); ends in bufB
    {
        const uint2* gin = (const uint2*)g0buf;
        for (int it = 0; it < 10; ++it) {
            uint2* go = (uint2*)((it & 1) ? bufB : bufA);
            conv_kernel<<<conv_blocks, 256, 0, stream>>>(gin, (const uint2*)g0buf, go,
                                                         deg, rowp, col, wdeg, N);
            gin = go;
        }
    }
    // out = (sq .* bufB) @ Wout + bout
    out_kernel<<<(N * 16 + 255) / 256, 256, 0, stream>>>(bufB, sq, Wout, bout, out, N);
}

// Round 6
// 679.216 us; speedup vs baseline: 2.6997x; 2.6997x over previous
//
#include <hip/hip_runtime.h>
#include <hip/hip_fp16.h>

#define NSLICE 8     // dst slices, mapped to XCDs via blockIdx & 7
#define EPB 2048     // edges scanned per block (256 threads x 8)

// ---------- preprocessing: padded-CSR build (exact degrees, no cap) ----------
// v6: fix v5's allocator. v5 did atomicAdd(&alloc8[slice], p) per NODE ->
// 100k device-scope same-address atomics to one line = 1137us serialized
// (counters: VALUBusy 0.03%, 7 GB/s). v6 aggregates hierarchically: per-block
// LDS counters absorb the 256 per-thread bumps, then <=2 global atomics per
// block (256-node span straddles at most one slice boundary) -> ~400 global
// atomics total. Row order within a slice region is irrelevant (only
// disjointness matters), so allocation order nondeterminism is harmless.

// pass 1: exact degree count. Block b: dst slice (b&7) -> XCD-local atomics.
__global__ __launch_bounds__(256) void count_kernel(
    const int* __restrict__ edges, int* __restrict__ deg,
    int e, int n, int slice_sz) {
    int slice = blockIdx.x & (NSLICE - 1);
    int chunk = blockIdx.x >> 3;
    int lo = slice * slice_sz;
    int hi = min(n, lo + slice_sz);
    int base = chunk * EPB + threadIdx.x;
    int d[EPB / 256];
#pragma unroll
    for (int k = 0; k < EPB / 256; ++k) {
        int i = base + k * 256;
        int valid = i < e;
        int ii = valid ? i : 0;       // safe address; result discarded if !valid
        int dv = edges[e + ii];       // independent batched dst loads
        d[k] = valid ? dv : -1;       // -1 fails every slice filter
    }
#pragma unroll
    for (int k = 0; k < EPB / 256; ++k) {
        int dv = d[k];
        if (dv < lo || dv >= hi) continue;
        atomicAdd(&deg[dv], 1);
    }
}

// pass 2: per-node constants + CSR row allocation (hierarchical bump) + padding.
// Row length padded to x8 with phantom node n (its g-row is zero -> adds 0).
__global__ __launch_bounds__(256) void nodeconst_kernel(
    const int* __restrict__ deg, int* __restrict__ alloc8,
    float* __restrict__ rs, float* __restrict__ sq,
    float* __restrict__ wdeg, int* __restrict__ rowp,
    int* __restrict__ cur, int* __restrict__ col,
    int n, int slice_sz, int rcap) {
    __shared__ int lds_cnt[NSLICE];
    __shared__ int lds_base[NSLICE];
    int tid = threadIdx.x;
    if (tid < NSLICE) lds_cnt[tid] = 0;
    __syncthreads();
    int i = blockIdx.x * blockDim.x + tid;
    int v = 0, p = 0, slice = 0, local = 0;
    bool active = (i <= n);
    if (active) {
        v = (i < n) ? deg[i] : 0;
        float d = (float)max(v, 1);
        float r = rsqrtf(d);
        rs[i] = r;
        sq[i] = sqrtf(d);
        wdeg[i] = 0.9f * r * r;
        p = (v + 7) & ~7;                        // padded row length
        slice = (i < n) ? (i / slice_sz) : 0;    // phantom: p=0, slice moot
        local = atomicAdd(&lds_cnt[slice], p);   // block-local offset
    }
    __syncthreads();
    if (tid < NSLICE) {
        int t = lds_cnt[tid];
        lds_base[tid] = t ? atomicAdd(&alloc8[tid], t) : 0;  // <=2 real ones/block
    }
    __syncthreads();
    if (active) {
        int base = slice * rcap + lds_base[slice] + local;
        rowp[i] = base;
        cur[i] = base;   // fill cursor starts at row base
        for (int k = v; k < p; ++k) col[base + k] = n;  // phantom padding
    }
}

// pass 3: CSR fill. Same slice/chunk decomposition as count; writes land in
// this slice's ~1MB col region -> L2-resident, no write-allocate thrash.
__global__ __launch_bounds__(256) void csr_fill(
    const int* __restrict__ edges, int* __restrict__ cur,
    int* __restrict__ col, int e, int n, int slice_sz, int rcap) {
    int slice = blockIdx.x & (NSLICE - 1);
    int chunk = blockIdx.x >> 3;
    int lo = slice * slice_sz;
    int hi = min(n, lo + slice_sz);
    int lim = (slice + 1) * rcap;   // region bound (OOB guard; never hit)
    int base = chunk * EPB + threadIdx.x;
    int d[EPB / 256], s[EPB / 256];
#pragma unroll
    for (int k = 0; k < EPB / 256; ++k) {
        int i = base + k * 256;
        int valid = i < e;
        int ii = valid ? i : 0;
        int dv = edges[e + ii];
        int sv = edges[ii];
        d[k] = valid ? dv : -1;
        s[k] = sv;
    }
#pragma unroll
    for (int k = 0; k < EPB / 256; ++k) {
        int dv = d[k];
        if (dv < lo || dv >= hi) continue;
        int slot = atomicAdd(&cur[dv], 1);
        if (slot < lim) col[slot] = s[k];
    }
}

// g = rs (.) x, fp32 -> fp16. One thread per feature pair. Covers phantom
// node n (writes zeros; never reads x out of bounds).
__global__ void prescale_kernel(const float2* __restrict__ x2, const float* __restrict__ rs,
                                __half2* __restrict__ g, int n) {
    int i = blockIdx.x * blockDim.x + threadIdx.x;
    int node = i >> 4;
    if (node > n) return;
    if (node == n) { g[i] = __floats2half2_rn(0.f, 0.f); return; }
    float2 v = x2[i];
    float r = rs[node];
    g[i] = __floats2half2_rn(v.x * r, v.y * r);
}

// ---------- g-space conv (fp16 rows, packed-fp16 partial accum, padded CSR) ---
// g_out[d] = wdeg[d] * sum_{s in N(d)} g[s] + 0.1 * g0[d]
// 8 lanes per node, lane owns 4 halfs (8B; 8 lanes = one 64B row = 1 line).
// 8-edge rounds; entries coop-loaded + __shfl(width=8) broadcast; 8 indep
// gathers/round. Accumulation: v_pk_add_f16 into 4 half2-pair chains,
// flushed to fp32 every 2 rounds (wave-uniform) + once after the loop.
// index stream is dense CSR (j0 = rowp[node]); plain (cached) loads.

union H4 {
    uint2 u;
    __half2 h[2];
};

__global__ __launch_bounds__(256) void conv_kernel(
    const uint2* __restrict__ gin, const uint2* __restrict__ g0,
    uint2* __restrict__ gout, const int* __restrict__ deg,
    const int* __restrict__ rowp, const int* __restrict__ col,
    const float* __restrict__ wdeg, int n) {
    int gid = blockIdx.x * blockDim.x + threadIdx.x;
    int node = gid >> 3;
    int q = gid & 7;
    if (node > n) return;  // phantom node n: deg 0 -> writes 0.1*g0 = 0
    int dg = (node < n) ? deg[node] : 0;
    int trips = (dg + 7) >> 3;  // rounds of 8 edges (CSR padded to x8)
    int j0 = rowp[node];
    float w = wdeg[node];
    H4 g0v;
    g0v.u = g0[gid];  // issued early; latency overlaps the loop
    // fp32 master accumulators
    float ax = 0.f, ay = 0.f, az = 0.f, aw = 0.f;
    // fp16 packed partial accumulators: 4 chains x 2 half2 (lo=feats01, hi=feats23)
    __half2 b0l = __floats2half2_rn(0.f, 0.f), b0h = b0l;
    __half2 b1l = b0l, b1h = b0l;
    __half2 b2l = b0l, b2h = b0l;
    __half2 b3l = b0l, b3h = b0l;
    int scur = col[j0 + q];  // unused if trips==0; region slack covers it
    for (int r = 0; r < trips; ++r) {
        int snext = col[j0 + (r + 1) * 8 + q];  // prefetch (dense; slack-padded)
        int s0 = __shfl(scur, 0, 8), s1 = __shfl(scur, 1, 8);
        int s2 = __shfl(scur, 2, 8), s3 = __shfl(scur, 3, 8);
        int s4 = __shfl(scur, 4, 8), s5 = __shfl(scur, 5, 8);
        int s6 = __shfl(scur, 6, 8), s7 = __shfl(scur, 7, 8);
        H4 v0, v1, v2, v3, v4, v5, v6, v7;
        v0.u = gin[(size_t)s0 * 8 + q];
        v1.u = gin[(size_t)s1 * 8 + q];
        v2.u = gin[(size_t)s2 * 8 + q];
        v3.u = gin[(size_t)s3 * 8 + q];
        v4.u = gin[(size_t)s4 * 8 + q];
        v5.u = gin[(size_t)s5 * 8 + q];
        v6.u = gin[(size_t)s6 * 8 + q];
        v7.u = gin[(size_t)s7 * 8 + q];
        b0l = __hadd2(b0l, v0.h[0]); b0h = __hadd2(b0h, v0.h[1]);
        b1l = __hadd2(b1l, v1.h[0]); b1h = __hadd2(b1h, v1.h[1]);
        b2l = __hadd2(b2l, v2.h[0]); b2h = __hadd2(b2h, v2.h[1]);
        b3l = __hadd2(b3l, v3.h[0]); b3h = __hadd2(b3h, v3.h[1]);
        b0l = __hadd2(b0l, v4.h[0]); b0h = __hadd2(b0h, v4.h[1]);
        b1l = __hadd2(b1l, v5.h[0]); b1h = __hadd2(b1h, v5.h[1]);
        b2l = __hadd2(b2l, v6.h[0]); b2h = __hadd2(b2h, v6.h[1]);
        b3l = __hadd2(b3l, v7.h[0]); b3h = __hadd2(b3h, v7.h[1]);
        if (r & 1) {  // wave-uniform flush every 2 rounds (max 16 fp16 adds)
            float2 t;
            t = __half22float2(b0l); ax += t.x; ay += t.y;
            t = __half22float2(b0h); az += t.x; aw += t.y;
            t = __half22float2(b1l); ax += t.x; ay += t.y;
            t = __half22float2(b1h); az += t.x; aw += t.y;
            t = __half22float2(b2l); ax += t.x; ay += t.y;
            t = __half22float2(b2h); az += t.x; aw += t.y;
            t = __half22float2(b3l); ax += t.x; ay += t.y;
            t = __half22float2(b3h); az += t.x; aw += t.y;
            b0l = __floats2half2_rn(0.f, 0.f); b0h = b0l;
            b1l = b0l; b1h = b0l;
            b2l = b0l; b2h = b0l;
            b3l = b0l; b3h = b0l;
        }
        scur = snext;
    }
    {   // final flush (covers trailing odd round; zeros if already flushed)
        float2 t;
        t = __half22float2(b0l); ax += t.x; ay += t.y;
        t = __half22float2(b0h); az += t.x; aw += t.y;
        t = __half22float2(b1l); ax += t.x; ay += t.y;
        t = __half22float2(b1h); az += t.x; aw += t.y;
        t = __half22float2(b2l); ax += t.x; ay += t.y;
        t = __half22float2(b2h); az += t.x; aw += t.y;
        t = __half22float2(b3l); ax += t.x; ay += t.y;
        t = __half22float2(b3h); az += t.x; aw += t.y;
    }
    float2 g0lo = __half22float2(g0v.h[0]);
    float2 g0hi = __half22float2(g0v.h[1]);
    float rx = w * ax + 0.1f * g0lo.x;
    float ry = w * ay + 0.1f * g0lo.y;
    float rz = w * az + 0.1f * g0hi.x;
    float rw = w * aw + 0.1f * g0hi.y;
    H4 o;
    o.h[0] = __floats2half2_rn(rx, ry);
    o.h[1] = __floats2half2_rn(rz, rw);
    gout[gid] = o.u;
}

// ---------- per-(node,feature) MLP, fused with g->h and h->g conversions ----------
// Covers phantom node n: writes zero (mlp(0) != 0, so explicit).

__global__ __launch_bounds__(256) void mlp_kernel(
    const __half* __restrict__ gin, __half* __restrict__ gout,
    const float* __restrict__ rs, const float* __restrict__ sq,
    const float* __restrict__ emb,   // [32][6]
    const float* __restrict__ W1,    // [7][9] row-major
    const float* __restrict__ b1,    // [9]
    const float* __restrict__ W2,    // [9]
    const float* __restrict__ b2,    // [1]
    int n) {
    __shared__ float c[32][9];
    __shared__ float w0[9], w2[9];
    __shared__ float b2s;
    int tid = threadIdx.x;
    for (int i = tid; i < 288; i += blockDim.x) {
        int f = i / 9, jj = i % 9;
        float acc = b1[jj];
#pragma unroll
        for (int k = 0; k < 6; ++k) acc += emb[f * 6 + k] * W1[(1 + k) * 9 + jj];
        c[f][jj] = acc;
    }
    if (tid < 9) { w0[tid] = W1[tid]; w2[tid] = W2[tid]; }
    if (tid == 0) b2s = b2[0];
    __syncthreads();
    int gid = blockIdx.x * blockDim.x + tid;
    int node = gid >> 5;
    if (node > n) return;
    if (node == n) { gout[gid] = __float2half_rn(0.f); return; }
    int f = gid & 31;
    float xv = __half2float(gin[gid]) * sq[node];
    float acc = b2s;
#pragma unroll
    for (int jj = 0; jj < 9; ++jj)
        acc += fmaxf(xv * w0[jj] + c[f][jj], 0.0f) * w2[jj];
    gout[gid] = __float2half_rn(acc * rs[node]);
}

// ---------- output projection (fused g->h): out = (sq .* g) @ Wout + bout ----------

__global__ __launch_bounds__(256) void out_kernel(
    const __half* __restrict__ g, const float* __restrict__ sq,
    const float* __restrict__ Wout, const float* __restrict__ bout,
    float* __restrict__ out, int n) {
    __shared__ float w[32 * 16];
    __shared__ float bo[16];
    int tid = threadIdx.x;
    for (int i = tid; i < 512; i += blockDim.x) w[i] = Wout[i];
    if (tid < 16) bo[tid] = bout[tid];
    __syncthreads();
    int gid = blockIdx.x * blockDim.x + tid;
    int node = gid >> 4;
    int cls = gid & 15;
    if (node >= n) return;
    const __half* gr = g + (size_t)node * 32;
    float acc = 0.0f;
#pragma unroll
    for (int f = 0; f < 32; ++f) acc += __half2float(gr[f]) * w[f * 16 + cls];
    out[gid] = acc * sq[node] + bo[cls];
}

extern "C" void kernel_launch(void* const* d_in, const int* in_sizes, int n_in,
                              void* d_out, int out_size, void* d_ws, size_t ws_size,
                              hipStream_t stream) {
    const float* x    = (const float*)d_in[0];
    const int* edges  = (const int*)d_in[1];
    const float* emb  = (const float*)d_in[2];
    const float* W1   = (const float*)d_in[3];
    const float* b1   = (const float*)d_in[4];
    const float* W2   = (const float*)d_in[5];
    const float* b2   = (const float*)d_in[6];
    const float* Wout = (const float*)d_in[7];
    const float* bout = (const float*)d_in[8];
    float* out        = (float*)d_out;

    const int N = in_sizes[0] / 32;
    const int E = in_sizes[1] / 2;

    const int slice_sz = (N + NSLICE - 1) / NSLICE;
    // per-slice col region capacity (ints): expected edges/slice (E/8) +
    // padding bound (<8*slice_sz) + skew/prefetch slack. Never overflows for
    // uniform-random dst (sigma ~ 420 edges); guarded in csr_fill anyway.
    const int RCAP = E / NSLICE + 8 * slice_sz + 4096;

    size_t off = 0;
    auto walloc = [&](size_t bytes) {
        void* p = (char*)d_ws + off;
        off += (bytes + 255) & ~(size_t)255;
        return p;
    };
    // all per-node arrays sized N+1 for the phantom (dummy) node N
    int*     deg   = (int*)    walloc((size_t)(N + 1 + 8) * 4);  // +8: alloc8
    int*     alloc8= deg + (N + 1);
    float*   rs    = (float*)  walloc((size_t)(N + 1) * 4);
    float*   sq    = (float*)  walloc((size_t)(N + 1) * 4);
    float*   wdeg  = (float*)  walloc((size_t)(N + 1) * 4);
    int*     rowp  = (int*)    walloc((size_t)(N + 1) * 4);
    int*     cur   = (int*)    walloc((size_t)(N + 1) * 4);
    int*     col   = (int*)    walloc((size_t)NSLICE * RCAP * 4 + 256);
    __half*  g0buf = (__half*) walloc((size_t)(N + 1) * 32 * 2);
    __half*  bufA  = (__half*) walloc((size_t)(N + 1) * 32 * 2);
    __half*  bufB  = (__half*) walloc((size_t)(N + 1) * 32 * 2);

    hipMemsetAsync(deg, 0, (size_t)(N + 1 + 8) * 4, stream);  // deg + alloc8

    const int chunks = (E + EPB - 1) / EPB;
    count_kernel<<<chunks * NSLICE, 256, 0, stream>>>(edges, deg, E, N, slice_sz);
    nodeconst_kernel<<<(N + 1 + 255) / 256, 256, 0, stream>>>(
        deg, alloc8, rs, sq, wdeg, rowp, cur, col, N, slice_sz, RCAP);
    csr_fill<<<chunks * NSLICE, 256, 0, stream>>>(edges, cur, col, E, N, slice_sz, RCAP);

    const int conv_blocks = ((N + 1) * 8 + 255) / 256;
    const int elem_blocks = ((N + 1) * 32 + 255) / 256;
    const int pair_blocks = ((N + 1) * 16 + 255) / 256;

    prescale_kernel<<<pair_blocks, 256, 0, stream>>>((const float2*)x, rs,
                                                     (__half2*)g0buf, N);

    // diffuse #1 in g-space (g0 = g0buf); 10 iters ends in bufB
    {
        const uint2* gin = (const uint2*)g0buf;
        for (int it = 0; it < 10; ++it) {
            uint2* go = (uint2*)((it & 1) ? bufB : bufA);
            conv_kernel<<<conv_blocks, 256, 0, stream>>>(gin, (const uint2*)g0buf, go,
                                                         deg, rowp, col, wdeg, N);
            gin = go;
        }
    }
    // MLP (g->h, mlp, h->g): bufB -> g0buf (becomes g0 of diffuse #2)
    mlp_kernel<<<elem_blocks, 256, 0, stream>>>(bufB, g0buf, rs, sq, emb, W1, b1, W2, b2, N);

    // diffuse #2 in g-space (g0 = g0buf); ends in bufB
    {
        const uint2* gin = (const uint2*)g0buf;
        for (int it = 0; it < 10; ++it) {
            uint2* go = (uint2*)((it & 1) ? bufB : bufA);
            conv_kernel<<<conv_blocks, 256, 0, stream>>>(gin, (const uint2*)g0buf, go,
                                                         deg, rowp, col, wdeg, N);
            gin = go;
        }
    }
    // out = (sq .* bufB) @ Wout + bout
    out_kernel<<<(N * 16 + 255) / 256, 256, 0, stream>>>(bufB, sq, Wout, bout, out, N);
}

// Round 8
// 618.650 us; speedup vs baseline: 2.9640x; 1.0979x over previous
//
#include <hip/hip_runtime.h>
#include <hip/hip_fp16.h>

#define ELL_CAP 64   // max degree slots per node; P(Poisson(16) >= 64) ~ 1e-18
#define NSLICE 8     // dst slices, mapped to XCDs via blockIdx & 7
#define EPB 2048     // edges scanned per block (256 threads x 8)

// ---------- preprocessing ----------

// XCD-affinity ELL build, single dispatch (proven one-pass form; CSR 3-pass
// experiment cost +52us net). The ~72us cost is an L2 atomic-RMW/latency
// floor: invariant across batched loads (R2), NT hints (R4), dense-CSR (R6).
__global__ __launch_bounds__(256) void ell_fill(
    const int* __restrict__ edges, int* __restrict__ deg,
    int* __restrict__ ell, int e, int n, int slice_sz) {
    int slice = blockIdx.x & (NSLICE - 1);
    int chunk = blockIdx.x >> 3;
    int lo = slice * slice_sz;
    int hi = min(n, lo + slice_sz);
    int base = chunk * EPB + threadIdx.x;
    int d[EPB / 256], s[EPB / 256];
#pragma unroll
    for (int k = 0; k < EPB / 256; ++k) {
        int i = base + k * 256;
        int valid = i < e;
        int ii = valid ? i : 0;          // safe address; result discarded if !valid
        int dv = edges[e + ii];          // independent batched dst loads
        int sv = edges[ii];              // independent batched src loads
        d[k] = valid ? dv : -1;          // -1 fails every slice filter
        s[k] = sv;
    }
#pragma unroll
    for (int k = 0; k < EPB / 256; ++k) {
        int dv = d[k];
        if (dv < lo || dv >= hi) continue;
        int slot = atomicAdd(&deg[dv], 1);
        if (slot < ELL_CAP) ell[((size_t)dv << 6) + slot] = s[k];
    }
}

// per-node constants + ELL row padding to a multiple of 8 with dummy node n.
// Dummy node's g-row is zero, so padded gathers add 0 (one hot line).
__global__ void nodeconst_kernel(const int* __restrict__ deg, float* __restrict__ rs,
                                 float* __restrict__ sq, float* __restrict__ wdeg,
                                 int* __restrict__ ell, int n) {
    int i = blockIdx.x * blockDim.x + threadIdx.x;
    if (i > n) return;  // includes phantom node n (deg 0)
    int v = (i < n) ? deg[i] : 0;
    float d = (float)max(v, 1);
    float r = rsqrtf(d);
    rs[i] = r;
    sq[i] = sqrtf(d);
    wdeg[i] = 0.9f * r * r;
    if (i < n) {
        int dg = min(v, ELL_CAP);
        int dgp = (dg + 7) & ~7;
        for (int k = dg; k < dgp; ++k) ell[((size_t)i << 6) + k] = n;  // dummy
    }
}

// g = rs (.) x, fp32 -> fp16. One thread per feature pair. Covers phantom
// node n (writes zeros; never reads x out of bounds).
__global__ void prescale_kernel(const float2* __restrict__ x2, const float* __restrict__ rs,
                                __half2* __restrict__ g, int n) {
    int i = blockIdx.x * blockDim.x + threadIdx.x;
    int node = i >> 4;
    if (node > n) return;
    if (node == n) { g[i] = __floats2half2_rn(0.f, 0.f); return; }
    float2 v = x2[i];
    float r = rs[node];
    g[i] = __floats2half2_rn(v.x * r, v.y * r);
}

// ---------- g-space conv, v7: 2-deep ping-pong gather pipeline ----------
// g_out[d] = wdeg[d] * sum_{s in N(d)} g[s] + 0.1 * g0[d]
// 8 lanes per node, lane owns 4 halfs (8B; 8 lanes = one 64B row = 1 line).
// v7 theory: at ~25us/conv the kernel is LATENCY-bound (22% BW, 6.5% VALU,
// ~37 outstanding lines/CU by Little's law), and the old loop drained all 8
// gathers before issuing the next trip's. Now trip r+1's gathers are issued
// BEFORE trip r is accumulated (A/B register ping-pong, indices fetched 2
// trips ahead). Beyond-end trips clamp their indices to phantom node n
// (zero row) -> unconditional issue, bit-identical accumulation order.
// (v7a: macros -> unrolled array helpers; ##-pasting broke on pp-numbers.)

union H4 {
    uint2 u;
    __half2 h[2];
};

__device__ __forceinline__ void issue8(H4 (&P)[8], int idx, const uint2* __restrict__ gin, int q) {
    int t[8];
#pragma unroll
    for (int l = 0; l < 8; ++l) t[l] = __shfl(idx, l, 8);
#pragma unroll
    for (int l = 0; l < 8; ++l) P[l].u = gin[(size_t)t[l] * 8 + q];
}

__device__ __forceinline__ void accum8(H4 (&P)[8], __half2& b0l, __half2& b0h,
                                       __half2& b1l, __half2& b1h,
                                       __half2& b2l, __half2& b2h,
                                       __half2& b3l, __half2& b3h) {
    b0l = __hadd2(b0l, P[0].h[0]); b0h = __hadd2(b0h, P[0].h[1]);
    b1l = __hadd2(b1l, P[1].h[0]); b1h = __hadd2(b1h, P[1].h[1]);
    b2l = __hadd2(b2l, P[2].h[0]); b2h = __hadd2(b2h, P[2].h[1]);
    b3l = __hadd2(b3l, P[3].h[0]); b3h = __hadd2(b3h, P[3].h[1]);
    b0l = __hadd2(b0l, P[4].h[0]); b0h = __hadd2(b0h, P[4].h[1]);
    b1l = __hadd2(b1l, P[5].h[0]); b1h = __hadd2(b1h, P[5].h[1]);
    b2l = __hadd2(b2l, P[6].h[0]); b2h = __hadd2(b2h, P[6].h[1]);
    b3l = __hadd2(b3l, P[7].h[0]); b3h = __hadd2(b3h, P[7].h[1]);
}

__global__ __launch_bounds__(256) void conv_kernel(
    const uint2* __restrict__ gin, const uint2* __restrict__ g0,
    uint2* __restrict__ gout, const int* __restrict__ deg,
    const int* __restrict__ ell, const float* __restrict__ wdeg, int n) {
    int gid = blockIdx.x * blockDim.x + threadIdx.x;
    int node = gid >> 3;
    int q = gid & 7;
    if (node > n) return;  // phantom node n: trips 0 -> writes 0.1*g0 = 0
    int dg = (node < n) ? min(deg[node], ELL_CAP) : 0;
    int trips = (dg + 7) >> 3;  // rounds of 8 edges (ELL padded to x8)
    int j0 = node << 6;
    float w = wdeg[node];
    H4 g0v;
    g0v.u = g0[gid];  // issued early; latency overlaps the loop
    // fp32 master accumulators
    float ax = 0.f, ay = 0.f, az = 0.f, aw = 0.f;
    // fp16 packed partial accumulators: 4 chains x 2 half2 (lo=feats01, hi=feats23)
    __half2 b0l = __floats2half2_rn(0.f, 0.f), b0h = b0l;
    __half2 b1l = b0l, b1h = b0l;
    __half2 b2l = b0l, b2h = b0l;
    __half2 b3l = b0l, b3h = b0l;

    // trip-r lane-q index; phantom n beyond actual trips (row reads stay
    // inside this node's 64-slot row via min, so addresses are always legal)
    auto ldidx = [&](int r) -> int {
        int v = ell[j0 + (min(r, 7) << 3) + q];
        return (r < trips) ? v : n;
    };

    if (trips > 0) {
        H4 A[8], B[8];
        int ia = ldidx(0);
        int ib = ldidx(1);
        issue8(A, ia, gin, q);   // trip 0 in flight
        issue8(B, ib, gin, q);   // trip 1 in flight
        int iters = (trips + 1) >> 1;
        for (int t = 0; t < iters; ++t) {
            int na = ldidx(2 * t + 2);   // next-A trip index (2 ahead of use)
            int nb = ldidx(2 * t + 3);
            accum8(A, b0l, b0h, b1l, b1h, b2l, b2h, b3l, b3h);  // waits on A only
            issue8(A, na, gin, q);       // refill A while B still in flight
            accum8(B, b0l, b0h, b1l, b1h, b2l, b2h, b3l, b3h);
            issue8(B, nb, gin, q);
            {   // flush every 2 trips (max 16 fp16 adds per chain-pair),
                // overlaps the in-flight A/B gathers
                float2 ft;
                ft = __half22float2(b0l); ax += ft.x; ay += ft.y;
                ft = __half22float2(b0h); az += ft.x; aw += ft.y;
                ft = __half22float2(b1l); ax += ft.x; ay += ft.y;
                ft = __half22float2(b1h); az += ft.x; aw += ft.y;
                ft = __half22float2(b2l); ax += ft.x; ay += ft.y;
                ft = __half22float2(b2h); az += ft.x; aw += ft.y;
                ft = __half22float2(b3l); ax += ft.x; ay += ft.y;
                ft = __half22float2(b3h); az += ft.x; aw += ft.y;
                b0l = __floats2half2_rn(0.f, 0.f); b0h = b0l;
                b1l = b0l; b1h = b0l;
                b2l = b0l; b2h = b0l;
                b3l = b0l; b3h = b0l;
            }
        }
    }

    float2 g0lo = __half22float2(g0v.h[0]);
    float2 g0hi = __half22float2(g0v.h[1]);
    float rx = w * ax + 0.1f * g0lo.x;
    float ry = w * ay + 0.1f * g0lo.y;
    float rz = w * az + 0.1f * g0hi.x;
    float rw = w * aw + 0.1f * g0hi.y;
    H4 o;
    o.h[0] = __floats2half2_rn(rx, ry);
    o.h[1] = __floats2half2_rn(rz, rw);
    gout[gid] = o.u;
}

// ---------- per-(node,feature) MLP, fused with g->h and h->g conversions ----------
// Covers phantom node n: writes zero (mlp(0) != 0, so explicit).

__global__ __launch_bounds__(256) void mlp_kernel(
    const __half* __restrict__ gin, __half* __restrict__ gout,
    const float* __restrict__ rs, const float* __restrict__ sq,
    const float* __restrict__ emb,   // [32][6]
    const float* __restrict__ W1,    // [7][9] row-major
    const float* __restrict__ b1,    // [9]
    const float* __restrict__ W2,    // [9]
    const float* __restrict__ b2,    // [1]
    int n) {
    __shared__ float c[32][9];
    __shared__ float w0[9], w2[9];
    __shared__ float b2s;
    int tid = threadIdx.x;
    for (int i = tid; i < 288; i += blockDim.x) {
        int f = i / 9, jj = i % 9;
        float acc = b1[jj];
#pragma unroll
        for (int k = 0; k < 6; ++k) acc += emb[f * 6 + k] * W1[(1 + k) * 9 + jj];
        c[f][jj] = acc;
    }
    if (tid < 9) { w0[tid] = W1[tid]; w2[tid] = W2[tid]; }
    if (tid == 0) b2s = b2[0];
    __syncthreads();
    int gid = blockIdx.x * blockDim.x + tid;
    int node = gid >> 5;
    if (node > n) return;
    if (node == n) { gout[gid] = __float2half_rn(0.f); return; }
    int f = gid & 31;
    float xv = __half2float(gin[gid]) * sq[node];
    float acc = b2s;
#pragma unroll
    for (int jj = 0; jj < 9; ++jj)
        acc += fmaxf(xv * w0[jj] + c[f][jj], 0.0f) * w2[jj];
    gout[gid] = __float2half_rn(acc * rs[node]);
}

// ---------- output projection (fused g->h): out = (sq .* g) @ Wout + bout ----------

__global__ __launch_bounds__(256) void out_kernel(
    const __half* __restrict__ g, const float* __restrict__ sq,
    const float* __restrict__ Wout, const float* __restrict__ bout,
    float* __restrict__ out, int n) {
    __shared__ float w[32 * 16];
    __shared__ float bo[16];
    int tid = threadIdx.x;
    for (int i = tid; i < 512; i += blockDim.x) w[i] = Wout[i];
    if (tid < 16) bo[tid] = bout[tid];
    __syncthreads();
    int gid = blockIdx.x * blockDim.x + tid;
    int node = gid >> 4;
    int cls = gid & 15;
    if (node >= n) return;
    const __half* gr = g + (size_t)node * 32;
    float acc = 0.0f;
#pragma unroll
    for (int f = 0; f < 32; ++f) acc += __half2float(gr[f]) * w[f * 16 + cls];
    out[gid] = acc * sq[node] + bo[cls];
}

extern "C" void kernel_launch(void* const* d_in, const int* in_sizes, int n_in,
                              void* d_out, int out_size, void* d_ws, size_t ws_size,
                              hipStream_t stream) {
    const float* x    = (const float*)d_in[0];
    const int* edges  = (const int*)d_in[1];
    const float* emb  = (const float*)d_in[2];
    const float* W1   = (const float*)d_in[3];
    const float* b1   = (const float*)d_in[4];
    const float* W2   = (const float*)d_in[5];
    const float* b2   = (const float*)d_in[6];
    const float* Wout = (const float*)d_in[7];
    const float* bout = (const float*)d_in[8];
    float* out        = (float*)d_out;

    const int N = in_sizes[0] / 32;
    const int E = in_sizes[1] / 2;

    size_t off = 0;
    auto walloc = [&](size_t bytes) {
        void* p = (char*)d_ws + off;
        off += (bytes + 255) & ~(size_t)255;
        return p;
    };
    // all per-node arrays sized N+1 for the phantom (dummy) node N
    int*     deg   = (int*)    walloc((size_t)(N + 1) * 4);
    float*   rs    = (float*)  walloc((size_t)(N + 1) * 4);
    float*   sq    = (float*)  walloc((size_t)(N + 1) * 4);
    float*   wdeg  = (float*)  walloc((size_t)(N + 1) * 4);
    int*     ell   = (int*)    walloc((size_t)(N + 1) * ELL_CAP * 4 + 256);
    __half*  g0buf = (__half*) walloc((size_t)(N + 1) * 32 * 2);
    __half*  bufA  = (__half*) walloc((size_t)(N + 1) * 32 * 2);
    __half*  bufB  = (__half*) walloc((size_t)(N + 1) * 32 * 2);

    hipMemsetAsync(deg, 0, (size_t)(N + 1) * 4, stream);
    // XCD-affinity ELL build: one dispatch, dst slice = blockIdx & 7
    {
        int slice_sz = (N + NSLICE - 1) / NSLICE;
        int chunks = (E + EPB - 1) / EPB;
        ell_fill<<<chunks * NSLICE, 256, 0, stream>>>(edges, deg, ell, E, N, slice_sz);
    }
    nodeconst_kernel<<<(N + 1 + 255) / 256, 256, 0, stream>>>(deg, rs, sq, wdeg, ell, N);

    const int conv_blocks = ((N + 1) * 8 + 255) / 256;
    const int elem_blocks = ((N + 1) * 32 + 255) / 256;
    const int pair_blocks = ((N + 1) * 16 + 255) / 256;

    prescale_kernel<<<pair_blocks, 256, 0, stream>>>((const float2*)x, rs,
                                                     (__half2*)g0buf, N);

    // diffuse #1 in g-space (g0 = g0buf); 10 iters ends in bufB
    {
        const uint2* gin = (const uint2*)g0buf;
        for (int it = 0; it < 10; ++it) {
            uint2* go = (uint2*)((it & 1) ? bufB : bufA);
            conv_kernel<<<conv_blocks, 256, 0, stream>>>(gin, (const uint2*)g0buf, go,
                                                         deg, ell, wdeg, N);
            gin = go;
        }
    }
    // MLP (g->h, mlp, h->g): bufB -> g0buf (becomes g0 of diffuse #2)
    mlp_kernel<<<elem_blocks, 256, 0, stream>>>(bufB, g0buf, rs, sq, emb, W1, b1, W2, b2, N);

    // diffuse #2 in g-space (g0 = g0buf); ends in bufB
    {
        const uint2* gin = (const uint2*)g0buf;
        for (int it = 0; it < 10; ++it) {
            uint2* go = (uint2*)((it & 1) ? bufB : bufA);
            conv_kernel<<<conv_blocks, 256, 0, stream>>>(gin, (const uint2*)g0buf, go,
                                                         deg, ell, wdeg, N);
            gin = go;
        }
    }
    // out = (sq .* bufB) @ Wout + bout
    out_kernel<<<(N * 16 + 255) / 256, 256, 0, stream>>>(bufB, sq, Wout, bout, out, N);
}